// Round 1
// baseline (278.400 us; speedup 1.0000x reference)
//
#include <hip/hip_runtime.h>
#include <math.h>

typedef unsigned short u16;
typedef short bf16x8 __attribute__((ext_vector_type(8)));   // 8 bf16 in 4 VGPR
typedef float f32x4 __attribute__((ext_vector_type(4)));
typedef float f32x4g __attribute__((ext_vector_type(4)));
typedef u16 u16x4 __attribute__((ext_vector_type(4)));

#define RATIO 0.0625f   // 256^-0.5
#define EPSK 1e-4f

__device__ __forceinline__ float bf2f(u16 u) {
  return __uint_as_float(((unsigned)u) << 16);
}
__device__ __forceinline__ u16 f2bf(float f) {
  unsigned x = __float_as_uint(f);
  x = x + 0x7fffu + ((x >> 16) & 1u);   // RNE
  return (u16)(x >> 16);
}
__device__ __forceinline__ unsigned fenc(float f) {  // order-preserving float->uint
  unsigned u = __float_as_uint(f);
  return (u & 0x80000000u) ? ~u : (u | 0x80000000u);
}
__device__ __forceinline__ float fdec(unsigned e) {
  return (e & 0x80000000u) ? __uint_as_float(e & 0x7fffffffu) : __uint_as_float(~e);
}

using as1v = __attribute__((address_space(1))) void;
using as3v = __attribute__((address_space(3))) void;
__device__ __forceinline__ void gl_lds16(const void* g, void* l) {
  // async global->LDS, 16B per lane; LDS dest = wave-uniform base + lane*16
  __builtin_amdgcn_global_load_lds((as1v*)g, (as3v*)l, 16, 0, 0);
}

// Stage a [128 x 32] bf16 tile (row-major, ld elems) into linear LDS.
// 8 chunks of 16 rows (1KB); each wave stages 2 chunks.
__device__ __forceinline__ void stage128x32(const u16* g, long row0, long k0, long ld,
                                            u16* lds, int l, int w) {
#pragma unroll
  for (int c = 0; c < 2; ++c) {
    int ch = w * 2 + c;
    long r = row0 + ch * 16 + (l >> 2);
    gl_lds16(g + r * ld + k0 + (long)(l & 3) * 8, lds + ch * 512);
  }
}

__device__ __forceinline__ void mma_step44(const u16* lA, const u16* lB, int rbase, int cbase,
                                           int l, f32x4 (&acc)[4][4]) {
  int lo = l & 15, hi = l >> 4;
  bf16x8 af[4], bb[4];
#pragma unroll
  for (int m = 0; m < 4; ++m)
    af[m] = *(const bf16x8*)(lA + (rbase + m * 16 + lo) * 32 + hi * 8);
#pragma unroll
  for (int n = 0; n < 4; ++n)
    bb[n] = *(const bf16x8*)(lB + (cbase + n * 16 + lo) * 32 + hi * 8);
#pragma unroll
  for (int m = 0; m < 4; ++m)
#pragma unroll
    for (int n = 0; n < 4; ++n)
      acc[m][n] = __builtin_amdgcn_mfma_f32_16x16x32_bf16(af[m], bb[n], acc[m][n], 0, 0, 0);
}

// ---------------- f32 -> bf16 convert (optionally scaled) ----------------
__global__ __launch_bounds__(256) void cvt_bf(const float* __restrict__ in, u16* __restrict__ out,
                                              long n, float scale) {
  long i = ((long)blockIdx.x * 256 + threadIdx.x) * 4;
  if (i >= n) return;
  f32x4 v = *(const f32x4*)(in + i);
  u16x4 o;
#pragma unroll
  for (int j = 0; j < 4; ++j) o[j] = f2bf(v[j] * scale);
  *(u16x4*)(out + i) = o;
}

// ---------------- QKV GEMM: C = X @ W^T (+bias); V stored transposed*mask ----------------
__global__ __launch_bounds__(256) void qkv_gemm(
    const u16* __restrict__ Xbf, const u16* __restrict__ Wbf,  // Wbf: [3072][1024]
    const float* __restrict__ bq, const float* __restrict__ bk, const float* __restrict__ bv,
    const float* __restrict__ mask,
    u16* __restrict__ Qbf, u16* __restrict__ Kbf, u16* __restrict__ Vt) {
  __shared__ u16 lA[2][128 * 32];
  __shared__ u16 lB[2][128 * 32];
  int tid = threadIdx.x, l = tid & 63, w = tid >> 6;
  long m0 = (long)blockIdx.x * 128;
  long c0 = (long)blockIdx.y * 128;
  f32x4 acc[4][4] = {};
  stage128x32(Xbf, m0, 0, 1024, lA[0], l, w);
  stage128x32(Wbf, c0, 0, 1024, lB[0], l, w);
  asm volatile("s_waitcnt vmcnt(0)" ::: "memory");
  __syncthreads();
  int cur = 0;
  for (int t = 0; t < 32; ++t) {
    if (t < 31) {
      stage128x32(Xbf, m0, (long)(t + 1) * 32, 1024, lA[cur ^ 1], l, w);
      stage128x32(Wbf, c0, (long)(t + 1) * 32, 1024, lB[cur ^ 1], l, w);
    }
    mma_step44(lA[cur], lB[cur], (w >> 1) * 64, (w & 1) * 64, l, acc);
    asm volatile("s_waitcnt vmcnt(0)" ::: "memory");
    __syncthreads();
    cur ^= 1;
  }
  int lo = l & 15, g = l >> 4;
  int wsel = (int)(c0 >> 10);  // 0=Q 1=K 2=V
  long cb = (c0 & 1023) + (w & 1) * 64;
  long rb = m0 + (w >> 1) * 64;
  if (wsel < 2) {
    const float* bias = wsel ? bk : bq;
    u16* O = wsel ? Kbf : Qbf;
#pragma unroll
    for (int m = 0; m < 4; ++m)
#pragma unroll
      for (int n = 0; n < 4; ++n) {
        long col = cb + n * 16 + lo;
        float bi = bias[col];
#pragma unroll
        for (int r = 0; r < 4; ++r) {
          long row = rb + m * 16 + g * 4 + r;
          O[row * 1024 + col] = f2bf(acc[m][n][r] + bi);
        }
      }
  } else {
#pragma unroll
    for (int m = 0; m < 4; ++m) {
      long t4 = rb + m * 16 + g * 4;  // 4 consecutive tokens, same b
      long b = t4 >> 12;
      long nn = t4 & 4095;
#pragma unroll
      for (int n = 0; n < 4; ++n) {
        long col = cb + n * 16 + lo;
        float bi = bv[col];
        long h = col >> 6, e = col & 63;
        u16x4 pk;
#pragma unroll
        for (int r = 0; r < 4; ++r) pk[r] = f2bf((acc[m][n][r] + bi) * mask[t4 + r]);
        *(u16x4*)&Vt[((b * 16 + h) * 64 + e) * 4096 + nn] = pk;
      }
    }
  }
}

// ---------------- feature kernel: dd = (QK/8)@proj^T per head; MODE 0=qp, 1=key max, 2=kp store ----------------
template <int MODE>
__global__ __launch_bounds__(256) void feat_kernel(
    const u16* __restrict__ QK, const u16* __restrict__ Pbf,  // Pbf = bf16(proj/8) [256][64]
    const float* __restrict__ mask, unsigned* __restrict__ menc, u16* __restrict__ out) {
  __shared__ u16 lP[256 * 64];  // 32KB
  __shared__ u16 lQ[64 * 64];   // 8KB
  __shared__ float sdiag[64];
  __shared__ float smask[64];
  __shared__ float sred[256];
  __shared__ float swmax[4];
  int tid = threadIdx.x, l = tid & 63, w = tid >> 6;
  int h = blockIdx.y;
  long t0 = (long)blockIdx.x * 64;
  int bh = (int)(t0 >> 12) * 16 + h;
#pragma unroll
  for (int i = 0; i < 8; ++i) {  // proj: 32 chunks of 8 rows (128B)
    int ch = w * 8 + i;
    gl_lds16(Pbf + (long)(ch * 8 + (l >> 3)) * 64 + (l & 7) * 8, lP + ch * 512);
  }
#pragma unroll
  for (int i = 0; i < 2; ++i) {  // Q/K tile: 8 chunks of 8 rows
    int ch = w * 2 + i;
    long tok = t0 + ch * 8 + (l >> 3);
    gl_lds16(QK + tok * 1024 + (long)h * 64 + (l & 7) * 8, lQ + ch * 512);
  }
  if (MODE != 0 && tid < 64) smask[tid] = mask[t0 + tid];
  asm volatile("s_waitcnt vmcnt(0)" ::: "memory");
  __syncthreads();
  if (MODE != 1) {  // diag = |row|^2 / 128 (raw; mask applied at epilogue for keys)
    int row = tid >> 2, q = tid & 3;
    float s = 0.f;
#pragma unroll
    for (int i = 0; i < 16; ++i) {
      float v = bf2f(lQ[row * 64 + q * 16 + i]);
      s += v * v;
    }
    sred[tid] = s;
    __syncthreads();
    if (tid < 64)
      sdiag[tid] = (sred[tid * 4] + sred[tid * 4 + 1] + sred[tid * 4 + 2] + sred[tid * 4 + 3]) * (1.f / 128.f);
    __syncthreads();
  }
  f32x4 acc[4][4] = {};
  int lo = l & 15, hi = l >> 4;
#pragma unroll
  for (int k2 = 0; k2 < 2; ++k2) {
    bf16x8 af[4], bb[4];
#pragma unroll
    for (int m = 0; m < 4; ++m)
      af[m] = *(const bf16x8*)(lQ + (m * 16 + lo) * 64 + k2 * 32 + hi * 8);
#pragma unroll
    for (int n = 0; n < 4; ++n)
      bb[n] = *(const bf16x8*)(lP + (w * 64 + n * 16 + lo) * 64 + k2 * 32 + hi * 8);
#pragma unroll
    for (int m = 0; m < 4; ++m)
#pragma unroll
      for (int n = 0; n < 4; ++n)
        acc[m][n] = __builtin_amdgcn_mfma_f32_16x16x32_bf16(af[m], bb[n], acc[m][n], 0, 0, 0);
  }
  int g = hi;
  if (MODE == 0) {
    float rmax[4][4];
#pragma unroll
    for (int m = 0; m < 4; ++m)
#pragma unroll
      for (int r = 0; r < 4; ++r) {
        float v = fmaxf(fmaxf(acc[m][0][r], acc[m][1][r]), fmaxf(acc[m][2][r], acc[m][3][r]));
        rmax[m][r] = v;
      }
#pragma unroll
    for (int s = 1; s <= 8; s <<= 1)
#pragma unroll
      for (int m = 0; m < 4; ++m)
#pragma unroll
        for (int r = 0; r < 4; ++r)
          rmax[m][r] = fmaxf(rmax[m][r], __shfl_xor(rmax[m][r], s, 64));
    if (lo == 0) {
#pragma unroll
      for (int m = 0; m < 4; ++m)
#pragma unroll
        for (int r = 0; r < 4; ++r) sred[(m * 16 + g * 4 + r) * 4 + w] = rmax[m][r];
    }
    __syncthreads();
#pragma unroll
    for (int m = 0; m < 4; ++m)
#pragma unroll
      for (int r = 0; r < 4; ++r) {
        int row = m * 16 + g * 4 + r;
        float mr = fmaxf(fmaxf(sred[row * 4], sred[row * 4 + 1]),
                         fmaxf(sred[row * 4 + 2], sred[row * 4 + 3]));
        float dg = sdiag[row];
        long n_ = (t0 & 4095) + row;
#pragma unroll
        for (int n = 0; n < 4; ++n) {
          float v = RATIO * (expf(acc[m][n][r] - dg - mr) + EPSK);
          out[((long)bh * 4096 + n_) * 256 + (w * 64 + n * 16 + lo)] = f2bf(v);
        }
      }
  } else if (MODE == 1) {
    float mm = -3.4e38f;
#pragma unroll
    for (int m = 0; m < 4; ++m)
#pragma unroll
      for (int r = 0; r < 4; ++r) {
        float mv = smask[m * 16 + g * 4 + r];
#pragma unroll
        for (int n = 0; n < 4; ++n) mm = fmaxf(mm, mv * acc[m][n][r]);
      }
#pragma unroll
    for (int s = 1; s < 64; s <<= 1) mm = fmaxf(mm, __shfl_xor(mm, s, 64));
    if (l == 0) swmax[w] = mm;
    __syncthreads();
    if (tid == 0) {
      float bm = fmaxf(fmaxf(swmax[0], swmax[1]), fmaxf(swmax[2], swmax[3]));
      atomicMax(&menc[bh], fenc(bm));
    }
  } else {
    float M = fdec(menc[bh]);
#pragma unroll
    for (int m = 0; m < 4; ++m) {
      long nb = (t0 & 4095) + m * 16 + g * 4;
#pragma unroll
      for (int n = 0; n < 4; ++n) {
        int col = w * 64 + n * 16 + lo;
        u16x4 pk;
#pragma unroll
        for (int r = 0; r < 4; ++r) {
          int row = m * 16 + g * 4 + r;
          float mv = smask[row];
          float v = RATIO * (expf(mv * acc[m][n][r] - mv * mv * sdiag[row] - M) + EPSK);
          pk[r] = f2bf(v);
        }
        *(u16x4*)&out[((long)bh * 256 + col) * 4096 + nb] = pk;  // kp transposed [r][n]
      }
    }
  }
}

// ---------------- k_sum = sum_n kp (also fills ctxb row 64, zeros rows 65..79) ----------------
__global__ __launch_bounds__(256) void ksum_kernel(const u16* __restrict__ kpt,
                                                   u16* __restrict__ ctxb) {
  int tid = threadIdx.x, l = tid & 63, w = tid >> 6;
  int bh = blockIdx.x >> 4, rg = blockIdx.x & 15;
#pragma unroll
  for (int i = 0; i < 4; ++i) {
    int r = rg * 16 + w * 4 + i;
    const u16* row = kpt + ((long)bh * 256 + r) * 4096;
    float s = 0.f;
#pragma unroll
    for (int j = 0; j < 8; ++j) {
      bf16x8 v = *(const bf16x8*)(row + j * 512 + l * 8);
#pragma unroll
      for (int e = 0; e < 8; ++e) s += bf2f((u16)v[e]);
    }
#pragma unroll
    for (int sft = 1; sft < 64; sft <<= 1) s += __shfl_xor(s, sft, 64);
    if (l == 0) ctxb[((long)bh * 80 + 64) * 256 + r] = f2bf(s);
  }
  if (rg == 0) {
    for (int i = tid; i < 15 * 256; i += 256) ctxb[((long)bh * 80 + 65) * 256 + i] = (u16)0;
  }
}

// ---------------- context: D[r][e] = sum_n kp_t[r][n] * Vt[e][n]; split-K partials ----------------
__global__ __launch_bounds__(256) void ctx_gemm(const u16* __restrict__ kpt,
                                                const u16* __restrict__ Vt,
                                                float* __restrict__ part) {
  __shared__ u16 lA[2][256 * 32];  // 16KB
  __shared__ u16 lB[2][64 * 32];   // 4KB
  int tid = threadIdx.x, l = tid & 63, w = tid >> 6;
  int bh = blockIdx.x, sp = blockIdx.y;
  long n0b = (long)sp * 512;
  f32x4 acc[4][4] = {};
  auto stage = [&](int t, int buf) {
    long n0 = n0b + (long)t * 32;
#pragma unroll
    for (int i = 0; i < 4; ++i) {
      int ch = w * 4 + i;
      int r = ch * 16 + (l >> 2);
      gl_lds16(kpt + ((long)bh * 256 + r) * 4096 + n0 + (l & 3) * 8, lA[buf] + ch * 512);
    }
    int r = w * 16 + (l >> 2);
    gl_lds16(Vt + ((long)bh * 64 + r) * 4096 + n0 + (l & 3) * 8, lB[buf] + w * 512);
  };
  stage(0, 0);
  asm volatile("s_waitcnt vmcnt(0)" ::: "memory");
  __syncthreads();
  int cur = 0;
  for (int t = 0; t < 16; ++t) {
    if (t < 15) stage(t + 1, cur ^ 1);
    int lo = l & 15, hi = l >> 4;
    bf16x8 af[4], bb[4];
#pragma unroll
    for (int m = 0; m < 4; ++m)
      af[m] = *(const bf16x8*)(lA[cur] + (w * 64 + m * 16 + lo) * 32 + hi * 8);
#pragma unroll
    for (int n = 0; n < 4; ++n)
      bb[n] = *(const bf16x8*)(lB[cur] + (n * 16 + lo) * 32 + hi * 8);
#pragma unroll
    for (int m = 0; m < 4; ++m)
#pragma unroll
      for (int n = 0; n < 4; ++n)
        acc[m][n] = __builtin_amdgcn_mfma_f32_16x16x32_bf16(af[m], bb[n], acc[m][n], 0, 0, 0);
    asm volatile("s_waitcnt vmcnt(0)" ::: "memory");
    __syncthreads();
    cur ^= 1;
  }
  int lo = l & 15, g = l >> 4;
#pragma unroll
  for (int m = 0; m < 4; ++m)
#pragma unroll
    for (int n = 0; n < 4; ++n) {
      int e = n * 16 + lo;
      int rb = w * 64 + m * 16 + g * 4;
      *(f32x4g*)&part[(((long)bh * 8 + sp) * 64 + e) * 256 + rb] = acc[m][n];  // [e][r] transposed
    }
}

__global__ __launch_bounds__(256) void ctx_reduce(const float* __restrict__ part,
                                                  u16* __restrict__ ctxb) {
  long t = (long)blockIdx.x * 256 + threadIdx.x;  // 32*64*256
  int r = (int)(t & 255);
  int e = (int)((t >> 8) & 63);
  int bh = (int)(t >> 14);
  float s = 0.f;
#pragma unroll
  for (int sp = 0; sp < 8; ++sp) s += part[(((long)bh * 8 + sp) * 64 + e) * 256 + r];
  ctxb[((long)bh * 80 + e) * 256 + r] = f2bf(s);
}

// ---------------- attn: D[tok][e] = sum_r qp[tok][r]*ctx[e][r]; col64 = denom; *D_inv ----------------
__global__ __launch_bounds__(256) void attn_gemm(const u16* __restrict__ qp,
                                                 const u16* __restrict__ ctxb,
                                                 u16* __restrict__ attn) {
  __shared__ u16 lA[2][128 * 32];  // 8KB
  __shared__ u16 lB[2][80 * 32];   // 5KB
  int tid = threadIdx.x, l = tid & 63, w = tid >> 6;
  int bh = blockIdx.x;
  long tokb = ((long)(bh >> 4)) << 12;
  long m0 = (long)blockIdx.y * 128;
  f32x4 acc[2][5] = {};
  auto stage = [&](int t, int buf) {
    long k0 = (long)t * 32;
#pragma unroll
    for (int i = 0; i < 2; ++i) {
      int ch = w * 2 + i;
      int r = ch * 16 + (l >> 2);
      gl_lds16(qp + ((long)bh * 4096 + m0 + r) * 256 + k0 + (l & 3) * 8, lA[buf] + ch * 512);
    }
    {
      int r = w * 16 + (l >> 2);
      gl_lds16(ctxb + ((long)bh * 80 + r) * 256 + k0 + (l & 3) * 8, lB[buf] + w * 512);
    }
    if (w == 0) {
      int r = 64 + (l >> 2);
      gl_lds16(ctxb + ((long)bh * 80 + r) * 256 + k0 + (l & 3) * 8, lB[buf] + 4 * 512);
    }
  };
  stage(0, 0);
  asm volatile("s_waitcnt vmcnt(0)" ::: "memory");
  __syncthreads();
  int cur = 0;
  for (int t = 0; t < 8; ++t) {
    if (t < 7) stage(t + 1, cur ^ 1);
    int lo = l & 15, hi = l >> 4;
    bf16x8 af[2], bb[5];
#pragma unroll
    for (int m = 0; m < 2; ++m)
      af[m] = *(const bf16x8*)(lA[cur] + (w * 32 + m * 16 + lo) * 32 + hi * 8);
#pragma unroll
    for (int n = 0; n < 5; ++n)
      bb[n] = *(const bf16x8*)(lB[cur] + (n * 16 + lo) * 32 + hi * 8);
#pragma unroll
    for (int m = 0; m < 2; ++m)
#pragma unroll
      for (int n = 0; n < 5; ++n)
        acc[m][n] = __builtin_amdgcn_mfma_f32_16x16x32_bf16(af[m], bb[n], acc[m][n], 0, 0, 0);
    asm volatile("s_waitcnt vmcnt(0)" ::: "memory");
    __syncthreads();
    cur ^= 1;
  }
  int lo = l & 15, g = l >> 4;
#pragma unroll
  for (int m = 0; m < 2; ++m) {
    float di[4];
#pragma unroll
    for (int r = 0; r < 4; ++r) {
      float dv = __shfl(acc[m][4][r], (l & 48), 64);  // denom from lane lo==0 of group
      di[r] = 1.f / dv;
    }
#pragma unroll
    for (int n = 0; n < 4; ++n) {
      int col = (bh & 15) * 64 + n * 16 + lo;
#pragma unroll
      for (int r = 0; r < 4; ++r) {
        long tok = tokb + m0 + w * 32 + m * 16 + g * 4 + r;
        attn[tok * 1024 + col] = f2bf(acc[m][n][r] * di[r]);
      }
    }
  }
}

// ---------------- FF GEMM: out = attn @ Wff^T + bias (f32 out) ----------------
__global__ __launch_bounds__(256) void ff_gemm(const u16* __restrict__ A,
                                               const u16* __restrict__ Wf,
                                               const float* __restrict__ bias,
                                               float* __restrict__ O) {
  __shared__ u16 lA[2][128 * 32];
  __shared__ u16 lB[2][128 * 32];
  int tid = threadIdx.x, l = tid & 63, w = tid >> 6;
  long m0 = (long)blockIdx.x * 128;
  long c0 = (long)blockIdx.y * 128;
  f32x4 acc[4][4] = {};
  stage128x32(A, m0, 0, 1024, lA[0], l, w);
  stage128x32(Wf, c0, 0, 1024, lB[0], l, w);
  asm volatile("s_waitcnt vmcnt(0)" ::: "memory");
  __syncthreads();
  int cur = 0;
  for (int t = 0; t < 32; ++t) {
    if (t < 31) {
      stage128x32(A, m0, (long)(t + 1) * 32, 1024, lA[cur ^ 1], l, w);
      stage128x32(Wf, c0, (long)(t + 1) * 32, 1024, lB[cur ^ 1], l, w);
    }
    mma_step44(lA[cur], lB[cur], (w >> 1) * 64, (w & 1) * 64, l, acc);
    asm volatile("s_waitcnt vmcnt(0)" ::: "memory");
    __syncthreads();
    cur ^= 1;
  }
  int lo = l & 15, g = l >> 4;
  long rb = m0 + (w >> 1) * 64;
  long cb = c0 + (w & 1) * 64;
#pragma unroll
  for (int m = 0; m < 4; ++m)
#pragma unroll
    for (int n = 0; n < 4; ++n) {
      long col = cb + n * 16 + lo;
      float bi = bias[col];
#pragma unroll
      for (int r = 0; r < 4; ++r) {
        long row = rb + m * 16 + g * 4 + r;
        O[row * 1024 + col] = acc[m][n][r] + bi;
      }
    }
}

extern "C" void kernel_launch(void* const* d_in, const int* in_sizes, int n_in,
                              void* d_out, int out_size, void* d_ws, size_t ws_size,
                              hipStream_t stream) {
  const float* X = (const float*)d_in[0];
  const float* mask = (const float*)d_in[1];
  const float* Wq = (const float*)d_in[2];
  const float* bq = (const float*)d_in[3];
  const float* Wk = (const float*)d_in[4];
  const float* bk = (const float*)d_in[5];
  const float* Wv = (const float*)d_in[6];
  const float* bv = (const float*)d_in[7];
  const float* Wff = (const float*)d_in[8];
  const float* bff = (const float*)d_in[9];
  const float* proj = (const float*)d_in[10];
  float* out = (float*)d_out;

  char* p = (char*)d_ws;
  u16* Xbf = (u16*)p;   p += 16777216;   // [8192][1024] bf16
  u16* Wqkv = (u16*)p;  p += 6291456;    // [3072][1024]
  u16* Wffb = (u16*)p;  p += 2097152;    // [1024][1024]
  u16* Pbf = (u16*)p;   p += 32768;      // bf16(proj/8) [256][64]
  u16* Qbf = (u16*)p;   p += 16777216;
  u16* Kbf = (u16*)p;   p += 16777216;
  u16* Vt = (u16*)p;    p += 16777216;   // [bh*64+e][4096] (mask applied)
  u16* qp = (u16*)p;    p += 67108864;   // [bh][4096][256]
  u16* kpt = (u16*)p;   p += 67108864;   // [bh][256][4096]
  u16* ctxb = (u16*)p;  p += 1310720;    // [bh][80][256]: rows 0-63 ctx^T, 64 k_sum, 65-79 zero
  unsigned* menc = (unsigned*)p; p += 256;
  float* ctxp = (float*)Qbf;  // 16.78MB partials, reuse (Qbf dead after feat<0>)
  u16* attn = Xbf;            // reuse (Xbf dead after qkv_gemm)

  hipMemsetAsync(menc, 0, 128, stream);
  cvt_bf<<<8192, 256, 0, stream>>>(X, Xbf, 8388608L, 1.f);
  cvt_bf<<<1024, 256, 0, stream>>>(Wq, Wqkv, 1048576L, 1.f);
  cvt_bf<<<1024, 256, 0, stream>>>(Wk, Wqkv + 1048576, 1048576L, 1.f);
  cvt_bf<<<1024, 256, 0, stream>>>(Wv, Wqkv + 2097152, 1048576L, 1.f);
  cvt_bf<<<1024, 256, 0, stream>>>(Wff, Wffb, 1048576L, 1.f);
  cvt_bf<<<16, 256, 0, stream>>>(proj, Pbf, 16384L, 0.125f);
  qkv_gemm<<<dim3(64, 24), 256, 0, stream>>>(Xbf, Wqkv, bq, bk, bv, mask, Qbf, Kbf, Vt);
  feat_kernel<0><<<dim3(128, 16), 256, 0, stream>>>(Qbf, Pbf, mask, menc, qp);
  feat_kernel<1><<<dim3(128, 16), 256, 0, stream>>>(Kbf, Pbf, mask, menc, kpt);
  feat_kernel<2><<<dim3(128, 16), 256, 0, stream>>>(Kbf, Pbf, mask, menc, kpt);
  ksum_kernel<<<512, 256, 0, stream>>>(kpt, ctxb);
  ctx_gemm<<<dim3(32, 8), 256, 0, stream>>>(kpt, Vt, ctxp);
  ctx_reduce<<<2048, 256, 0, stream>>>(ctxp, ctxb);
  attn_gemm<<<dim3(32, 32), 256, 0, stream>>>(qp, ctxb, attn);
  ff_gemm<<<dim3(64, 8), 256, 0, stream>>>(attn, Wffb, bff, out);
}

// Round 2
// 251.152 us; speedup vs baseline: 1.1085x; 1.1085x over previous
//
#include <hip/hip_runtime.h>
#include <math.h>

typedef unsigned short u16;
typedef short bf16x8 __attribute__((ext_vector_type(8)));   // 8 bf16 in 4 VGPR
typedef float f32x4 __attribute__((ext_vector_type(4)));
typedef u16 u16x4 __attribute__((ext_vector_type(4)));

#define RATIO 0.0625f   // 256^-0.5
#define EPSK 1e-4f

__device__ __forceinline__ float bf2f(u16 u) {
  return __uint_as_float(((unsigned)u) << 16);
}
__device__ __forceinline__ u16 f2bf(float f) {
  unsigned x = __float_as_uint(f);
  x = x + 0x7fffu + ((x >> 16) & 1u);   // RNE
  return (u16)(x >> 16);
}
__device__ __forceinline__ unsigned fenc(float f) {  // order-preserving float->uint
  unsigned u = __float_as_uint(f);
  return (u & 0x80000000u) ? ~u : (u | 0x80000000u);
}
__device__ __forceinline__ float fdec(unsigned e) {
  return (e & 0x80000000u) ? __uint_as_float(e & 0x7fffffffu) : __uint_as_float(~e);
}

using as1v = __attribute__((address_space(1))) void;
using as3v = __attribute__((address_space(3))) void;
__device__ __forceinline__ void gl_lds16(const void* g, void* l) {
  __builtin_amdgcn_global_load_lds((as1v*)g, (as3v*)l, 16, 0, 0);
}

// ---------------- f32 -> bf16 convert (optionally scaled) ----------------
__global__ __launch_bounds__(256) void cvt_bf(const float* __restrict__ in, u16* __restrict__ out,
                                              long n, float scale) {
  long i = ((long)blockIdx.x * 256 + threadIdx.x) * 4;
  if (i >= n) return;
  f32x4 v = *(const f32x4*)(in + i);
  u16x4 o;
#pragma unroll
  for (int j = 0; j < 4; ++j) o[j] = f2bf(v[j] * scale);
  *(u16x4*)(out + i) = o;
}

// =====================================================================
// 8-phase GEMM, 256x128 tile, BK=64, 8 waves (4M x 2N), 64x64 per wave.
// Triple-buffered LDS (race-free counted vmcnt(6), staging 2 tiles ahead).
// LDS layout per buffer: unit0 = A rows 0-127, unit1 = A rows 128-255,
// unit2 = B rows 0-127; each unit [128][64] bf16 with read-side XOR swizzle
// byte ^= (row&7)<<4 and pre-swizzled global source on the gl_lds16 side.
// EPI 0 = qkv (bias; Q/K row-major store, V transposed*mask), EPI 1 = ff.
// =====================================================================
template <int EPI, int NB>
__global__ __launch_bounds__(512, 1) void gemm8p(
    const u16* __restrict__ A, const u16* __restrict__ Bw,
    const float* __restrict__ bq, const float* __restrict__ bk,
    const float* __restrict__ bv, const float* __restrict__ mask,
    u16* __restrict__ Q, u16* __restrict__ Kb, u16* __restrict__ Vt,
    float* __restrict__ Of, const float* __restrict__ bff) {
  __shared__ __align__(16) u16 lds[3 * 3 * 8192];  // 144 KB
  const int nt = 16;  // K = 1024, BK = 64
  int tid = threadIdx.x;
  int l = tid & 63, w = tid >> 6;
  int wm = w >> 1, wn = w & 1;
  int lo = l & 15, hi = l >> 4;
  int bid = blockIdx.x;
  int swz = (bid & 7) * ((NB * 32) / 8) + (bid >> 3);  // bijective XCD swizzle
  long m0 = (long)(swz / NB) * 256;
  long c0 = (long)(swz % NB) * 128;
  int srow = tid >> 3;                              // staging row 0..63
  int sce = ((tid & 7) ^ ((tid >> 3) & 7)) * 8;     // pre-swizzled source col
  f32x4 acc[4][4] = {};

  auto stageA = [&](int t) {
    u16* ub = (u16*)lds + (t % 3) * 24576;
    long k0 = (long)t * 64;
#pragma unroll
    for (int u = 0; u < 2; ++u)
#pragma unroll
      for (int j = 0; j < 2; ++j) {
        long row = m0 + u * 128 + j * 64 + srow;
        gl_lds16(A + row * 1024 + k0 + sce, ub + u * 8192 + j * 4096 + tid * 8);
      }
  };
  auto stageB = [&](int t) {
    u16* ub = (u16*)lds + (t % 3) * 24576 + 16384;
    long k0 = (long)t * 64;
#pragma unroll
    for (int j = 0; j < 2; ++j) {
      long row = c0 + j * 64 + srow;
      gl_lds16(Bw + row * 1024 + k0 + sce, ub + j * 4096 + tid * 8);
    }
  };

  // prologue: tiles 0 and 1 in flight; wait tile 0 (leave tile 1's 6 loads)
  stageA(0); stageB(0);
  stageA(1); stageB(1);
  asm volatile("s_waitcnt vmcnt(6)" ::: "memory");
  __builtin_amdgcn_s_barrier();
  __builtin_amdgcn_sched_barrier(0);

  bf16x8 areg[4][2], breg[2][2];
  int arb = (wm & 1) * 64;
  for (int t = 0; t < nt; ++t) {
    const u16* Au = (const u16*)lds + (t % 3) * 24576 + (wm >> 1) * 8192;
    const u16* Bu = (const u16*)lds + (t % 3) * 24576 + 16384;
    // ---- phase 0: read A (8) + B n0-1 (4); stage A(t+2); MFMA n0-1 ----
#pragma unroll
    for (int mf = 0; mf < 4; ++mf) {
      int lrow = arb + mf * 16 + lo;
#pragma unroll
      for (int kk = 0; kk < 2; ++kk)
        areg[mf][kk] = *(const bf16x8*)(Au + lrow * 64 + ((kk * 32 + hi * 8) ^ ((lo & 7) << 3)));
    }
#pragma unroll
    for (int nf = 0; nf < 2; ++nf) {
      int lrow = wn * 64 + nf * 16 + lo;
#pragma unroll
      for (int kk = 0; kk < 2; ++kk)
        breg[nf][kk] = *(const bf16x8*)(Bu + lrow * 64 + ((kk * 32 + hi * 8) ^ ((lo & 7) << 3)));
    }
    if (t + 2 < nt) stageA(t + 2);
    __builtin_amdgcn_s_barrier();
    asm volatile("s_waitcnt lgkmcnt(0)" ::: "memory");
    __builtin_amdgcn_sched_barrier(0);
    __builtin_amdgcn_s_setprio(1);
#pragma unroll
    for (int mf = 0; mf < 4; ++mf)
#pragma unroll
      for (int nf = 0; nf < 2; ++nf)
#pragma unroll
        for (int kk = 0; kk < 2; ++kk)
          acc[mf][nf] = __builtin_amdgcn_mfma_f32_16x16x32_bf16(areg[mf][kk], breg[nf][kk],
                                                                acc[mf][nf], 0, 0, 0);
    __builtin_amdgcn_s_setprio(0);
    __builtin_amdgcn_s_barrier();
    __builtin_amdgcn_sched_barrier(0);
    // ---- phase 1: read B n2-3 (4); stage B(t+2); counted vmcnt; MFMA n2-3 ----
#pragma unroll
    for (int nf = 0; nf < 2; ++nf) {
      int lrow = wn * 64 + (2 + nf) * 16 + lo;
#pragma unroll
      for (int kk = 0; kk < 2; ++kk)
        breg[nf][kk] = *(const bf16x8*)(Bu + lrow * 64 + ((kk * 32 + hi * 8) ^ ((lo & 7) << 3)));
    }
    if (t + 2 < nt) {
      stageB(t + 2);
      asm volatile("s_waitcnt vmcnt(6)" ::: "memory");  // tile t+1 complete, t+2 in flight
    } else if (t + 1 < nt) {
      asm volatile("s_waitcnt vmcnt(0)" ::: "memory");  // tail drain (once)
    }
    __builtin_amdgcn_s_barrier();
    asm volatile("s_waitcnt lgkmcnt(0)" ::: "memory");
    __builtin_amdgcn_sched_barrier(0);
    __builtin_amdgcn_s_setprio(1);
#pragma unroll
    for (int mf = 0; mf < 4; ++mf)
#pragma unroll
      for (int nf = 0; nf < 2; ++nf)
#pragma unroll
        for (int kk = 0; kk < 2; ++kk)
          acc[mf][2 + nf] = __builtin_amdgcn_mfma_f32_16x16x32_bf16(areg[mf][kk], breg[nf][kk],
                                                                    acc[mf][2 + nf], 0, 0, 0);
    __builtin_amdgcn_s_setprio(0);
    __builtin_amdgcn_s_barrier();
    __builtin_amdgcn_sched_barrier(0);
  }

  // ---- epilogue ----
  long rowb = m0 + wm * 64;
  if (EPI == 0) {
    int wsel = (int)(c0 >> 10);  // 0=Q 1=K 2=V
    long cw = c0 & 1023;
    if (wsel < 2) {
      const float* bias = wsel ? bk : bq;
      u16* O = wsel ? Kb : Q;
#pragma unroll
      for (int mf = 0; mf < 4; ++mf)
#pragma unroll
        for (int nf = 0; nf < 4; ++nf) {
          long col = cw + wn * 64 + nf * 16 + lo;
          float bi = bias[col];
#pragma unroll
          for (int r = 0; r < 4; ++r) {
            long row = rowb + mf * 16 + hi * 4 + r;
            O[row * 1024 + col] = f2bf(acc[mf][nf][r] + bi);
          }
        }
    } else {
#pragma unroll
      for (int mf = 0; mf < 4; ++mf) {
        long t4 = rowb + mf * 16 + hi * 4;  // 4 consecutive tokens
        long b = t4 >> 12;
        long nn = t4 & 4095;
#pragma unroll
        for (int nf = 0; nf < 4; ++nf) {
          long col = cw + wn * 64 + nf * 16 + lo;
          float bi = bv[col];
          long h = col >> 6, e = col & 63;
          u16x4 pk;
#pragma unroll
          for (int r = 0; r < 4; ++r) pk[r] = f2bf((acc[mf][nf][r] + bi) * mask[t4 + r]);
          *(u16x4*)&Vt[((b * 16 + h) * 64 + e) * 4096 + nn] = pk;
        }
      }
    }
  } else {
#pragma unroll
    for (int mf = 0; mf < 4; ++mf)
#pragma unroll
      for (int nf = 0; nf < 4; ++nf) {
        long col = c0 + wn * 64 + nf * 16 + lo;
        float bi = bff[col];
#pragma unroll
        for (int r = 0; r < 4; ++r) {
          long row = rowb + mf * 16 + hi * 4 + r;
          Of[row * 1024 + col] = acc[mf][nf][r] + bi;
        }
      }
  }
}

// ---------------- feature kernel: dd = (QK/8)@proj^T per head; MODE 0=qp, 1=key max, 2=kp store ----------------
template <int MODE>
__global__ __launch_bounds__(256) void feat_kernel(
    const u16* __restrict__ QK, const u16* __restrict__ Pbf,  // Pbf = bf16(proj/8) [256][64]
    const float* __restrict__ mask, unsigned* __restrict__ menc, u16* __restrict__ out) {
  __shared__ u16 lP[256 * 64];  // 32KB
  __shared__ u16 lQ[64 * 64];   // 8KB
  __shared__ float sdiag[64];
  __shared__ float smask[64];
  __shared__ float sred[256];
  __shared__ float swmax[4];
  int tid = threadIdx.x, l = tid & 63, w = tid >> 6;
  int h = blockIdx.y;
  long t0 = (long)blockIdx.x * 64;
  int bh = (int)(t0 >> 12) * 16 + h;
#pragma unroll
  for (int i = 0; i < 8; ++i) {  // proj: 32 chunks of 8 rows (128B)
    int ch = w * 8 + i;
    gl_lds16(Pbf + (long)(ch * 8 + (l >> 3)) * 64 + (l & 7) * 8, lP + ch * 512);
  }
#pragma unroll
  for (int i = 0; i < 2; ++i) {  // Q/K tile: 8 chunks of 8 rows
    int ch = w * 2 + i;
    long tok = t0 + ch * 8 + (l >> 3);
    gl_lds16(QK + tok * 1024 + (long)h * 64 + (l & 7) * 8, lQ + ch * 512);
  }
  if (MODE != 0 && tid < 64) smask[tid] = mask[t0 + tid];
  asm volatile("s_waitcnt vmcnt(0)" ::: "memory");
  __syncthreads();
  if (MODE != 1) {  // diag = |row|^2 / 128 (raw; mask applied at epilogue for keys)
    int row = tid >> 2, q = tid & 3;
    float s = 0.f;
#pragma unroll
    for (int i = 0; i < 16; ++i) {
      float v = bf2f(lQ[row * 64 + q * 16 + i]);
      s += v * v;
    }
    sred[tid] = s;
    __syncthreads();
    if (tid < 64)
      sdiag[tid] = (sred[tid * 4] + sred[tid * 4 + 1] + sred[tid * 4 + 2] + sred[tid * 4 + 3]) * (1.f / 128.f);
    __syncthreads();
  }
  f32x4 acc[4][4] = {};
  int lo = l & 15, hi = l >> 4;
#pragma unroll
  for (int k2 = 0; k2 < 2; ++k2) {
    bf16x8 af[4], bb[4];
#pragma unroll
    for (int m = 0; m < 4; ++m)
      af[m] = *(const bf16x8*)(lQ + (m * 16 + lo) * 64 + k2 * 32 + hi * 8);
#pragma unroll
    for (int n = 0; n < 4; ++n)
      bb[n] = *(const bf16x8*)(lP + (w * 64 + n * 16 + lo) * 64 + k2 * 32 + hi * 8);
#pragma unroll
    for (int m = 0; m < 4; ++m)
#pragma unroll
      for (int n = 0; n < 4; ++n)
        acc[m][n] = __builtin_amdgcn_mfma_f32_16x16x32_bf16(af[m], bb[n], acc[m][n], 0, 0, 0);
  }
  int g = hi;
  if (MODE == 0) {
    float rmax[4][4];
#pragma unroll
    for (int m = 0; m < 4; ++m)
#pragma unroll
      for (int r = 0; r < 4; ++r) {
        float v = fmaxf(fmaxf(acc[m][0][r], acc[m][1][r]), fmaxf(acc[m][2][r], acc[m][3][r]));
        rmax[m][r] = v;
      }
#pragma unroll
    for (int s = 1; s <= 8; s <<= 1)
#pragma unroll
      for (int m = 0; m < 4; ++m)
#pragma unroll
        for (int r = 0; r < 4; ++r)
          rmax[m][r] = fmaxf(rmax[m][r], __shfl_xor(rmax[m][r], s, 64));
    if (lo == 0) {
#pragma unroll
      for (int m = 0; m < 4; ++m)
#pragma unroll
        for (int r = 0; r < 4; ++r) sred[(m * 16 + g * 4 + r) * 4 + w] = rmax[m][r];
    }
    __syncthreads();
#pragma unroll
    for (int m = 0; m < 4; ++m)
#pragma unroll
      for (int r = 0; r < 4; ++r) {
        int row = m * 16 + g * 4 + r;
        float mr = fmaxf(fmaxf(sred[row * 4], sred[row * 4 + 1]),
                         fmaxf(sred[row * 4 + 2], sred[row * 4 + 3]));
        float dg = sdiag[row];
        long n_ = (t0 & 4095) + row;
#pragma unroll
        for (int n = 0; n < 4; ++n) {
          float v = RATIO * (expf(acc[m][n][r] - dg - mr) + EPSK);
          out[((long)bh * 4096 + n_) * 256 + (w * 64 + n * 16 + lo)] = f2bf(v);
        }
      }
  } else if (MODE == 1) {
    float mm = -3.4e38f;
#pragma unroll
    for (int m = 0; m < 4; ++m)
#pragma unroll
      for (int r = 0; r < 4; ++r) {
        float mv = smask[m * 16 + g * 4 + r];
#pragma unroll
        for (int n = 0; n < 4; ++n) mm = fmaxf(mm, mv * acc[m][n][r]);
      }
#pragma unroll
    for (int s = 1; s < 64; s <<= 1) mm = fmaxf(mm, __shfl_xor(mm, s, 64));
    if (l == 0) swmax[w] = mm;
    __syncthreads();
    if (tid == 0) {
      float bm = fmaxf(fmaxf(swmax[0], swmax[1]), fmaxf(swmax[2], swmax[3]));
      atomicMax(&menc[bh], fenc(bm));
    }
  } else {
    float M = fdec(menc[bh]);
#pragma unroll
    for (int m = 0; m < 4; ++m) {
      long nb = (t0 & 4095) + m * 16 + g * 4;
#pragma unroll
      for (int n = 0; n < 4; ++n) {
        int col = w * 64 + n * 16 + lo;
        u16x4 pk;
#pragma unroll
        for (int r = 0; r < 4; ++r) {
          int row = m * 16 + g * 4 + r;
          float mv = smask[row];
          float v = RATIO * (expf(mv * acc[m][n][r] - mv * mv * sdiag[row] - M) + EPSK);
          pk[r] = f2bf(v);
        }
        *(u16x4*)&out[((long)bh * 256 + col) * 4096 + nb] = pk;  // kp transposed [r][n]
      }
    }
  }
}

// ---------------- k_sum = sum_n kp (also fills ctxb row 64, zeros rows 65..79) ----------------
__global__ __launch_bounds__(256) void ksum_kernel(const u16* __restrict__ kpt,
                                                   u16* __restrict__ ctxb) {
  int tid = threadIdx.x, l = tid & 63, w = tid >> 6;
  int bh = blockIdx.x >> 4, rg = blockIdx.x & 15;
#pragma unroll
  for (int i = 0; i < 4; ++i) {
    int r = rg * 16 + w * 4 + i;
    const u16* row = kpt + ((long)bh * 256 + r) * 4096;
    float s = 0.f;
#pragma unroll
    for (int j = 0; j < 8; ++j) {
      bf16x8 v = *(const bf16x8*)(row + j * 512 + l * 8);
#pragma unroll
      for (int e = 0; e < 8; ++e) s += bf2f((u16)v[e]);
    }
#pragma unroll
    for (int sft = 1; sft < 64; sft <<= 1) s += __shfl_xor(s, sft, 64);
    if (l == 0) ctxb[((long)bh * 80 + 64) * 256 + r] = f2bf(s);
  }
  if (rg == 0) {
    for (int i = tid; i < 15 * 256; i += 256) ctxb[((long)bh * 80 + 65) * 256 + i] = (u16)0;
  }
}

// ---------------- context: D[r][e] = sum_n kp_t[r][n] * Vt[e][n]; split-K partials ----------------
__global__ __launch_bounds__(256) void ctx_gemm(const u16* __restrict__ kpt,
                                                const u16* __restrict__ Vt,
                                                float* __restrict__ part) {
  __shared__ u16 lA[2][256 * 32];  // 16KB
  __shared__ u16 lB[2][64 * 32];   // 4KB
  int tid = threadIdx.x, l = tid & 63, w = tid >> 6;
  int bh = blockIdx.x, sp = blockIdx.y;
  long n0b = (long)sp * 512;
  f32x4 acc[4][4] = {};
  auto stage = [&](int t, int buf) {
    long n0 = n0b + (long)t * 32;
#pragma unroll
    for (int i = 0; i < 4; ++i) {
      int ch = w * 4 + i;
      int r = ch * 16 + (l >> 2);
      gl_lds16(kpt + ((long)bh * 256 + r) * 4096 + n0 + (l & 3) * 8, lA[buf] + ch * 512);
    }
    int r = w * 16 + (l >> 2);
    gl_lds16(Vt + ((long)bh * 64 + r) * 4096 + n0 + (l & 3) * 8, lB[buf] + w * 512);
  };
  stage(0, 0);
  asm volatile("s_waitcnt vmcnt(0)" ::: "memory");
  __syncthreads();
  int cur = 0;
  for (int t = 0; t < 16; ++t) {
    if (t < 15) stage(t + 1, cur ^ 1);
    int lo = l & 15, hi = l >> 4;
    bf16x8 af[4], bb[4];
#pragma unroll
    for (int m = 0; m < 4; ++m)
      af[m] = *(const bf16x8*)(lA[cur] + (w * 64 + m * 16 + lo) * 32 + hi * 8);
#pragma unroll
    for (int n = 0; n < 4; ++n)
      bb[n] = *(const bf16x8*)(lB[cur] + (n * 16 + lo) * 32 + hi * 8);
#pragma unroll
    for (int m = 0; m < 4; ++m)
#pragma unroll
      for (int n = 0; n < 4; ++n)
        acc[m][n] = __builtin_amdgcn_mfma_f32_16x16x32_bf16(af[m], bb[n], acc[m][n], 0, 0, 0);
    asm volatile("s_waitcnt vmcnt(0)" ::: "memory");
    __syncthreads();
    cur ^= 1;
  }
  int lo = l & 15, g = l >> 4;
#pragma unroll
  for (int m = 0; m < 4; ++m)
#pragma unroll
    for (int n = 0; n < 4; ++n) {
      int e = n * 16 + lo;
      int rb = w * 64 + m * 16 + g * 4;
      *(f32x4*)&part[(((long)bh * 8 + sp) * 64 + e) * 256 + rb] = acc[m][n];  // [e][r] transposed
    }
}

__global__ __launch_bounds__(256) void ctx_reduce(const float* __restrict__ part,
                                                  u16* __restrict__ ctxb) {
  long t = (long)blockIdx.x * 256 + threadIdx.x;  // 32*64*256
  int r = (int)(t & 255);
  int e = (int)((t >> 8) & 63);
  int bh = (int)(t >> 14);
  float s = 0.f;
#pragma unroll
  for (int sp = 0; sp < 8; ++sp) s += part[(((long)bh * 8 + sp) * 64 + e) * 256 + r];
  ctxb[((long)bh * 80 + e) * 256 + r] = f2bf(s);
}

// ---------------- attn: D[tok][e] = sum_r qp[tok][r]*ctx[e][r]; col64 = denom; *D_inv ----------------
__global__ __launch_bounds__(256) void attn_gemm(const u16* __restrict__ qp,
                                                 const u16* __restrict__ ctxb,
                                                 u16* __restrict__ attn) {
  __shared__ u16 lA[2][128 * 32];  // 8KB
  __shared__ u16 lB[2][80 * 32];   // 5KB
  int tid = threadIdx.x, l = tid & 63, w = tid >> 6;
  int bh = blockIdx.x;
  long tokb = ((long)(bh >> 4)) << 12;
  long m0 = (long)blockIdx.y * 128;
  f32x4 acc[2][5] = {};
  auto stage = [&](int t, int buf) {
    long k0 = (long)t * 32;
#pragma unroll
    for (int i = 0; i < 2; ++i) {
      int ch = w * 2 + i;
      int r = ch * 16 + (l >> 2);
      gl_lds16(qp + ((long)bh * 4096 + m0 + r) * 256 + k0 + (l & 3) * 8, lA[buf] + ch * 512);
    }
    {
      int r = w * 16 + (l >> 2);
      gl_lds16(ctxb + ((long)bh * 80 + r) * 256 + k0 + (l & 3) * 8, lB[buf] + w * 512);
    }
    if (w == 0) {
      int r = 64 + (l >> 2);
      gl_lds16(ctxb + ((long)bh * 80 + r) * 256 + k0 + (l & 3) * 8, lB[buf] + 4 * 512);
    }
  };
  stage(0, 0);
  asm volatile("s_waitcnt vmcnt(0)" ::: "memory");
  __syncthreads();
  int cur = 0;
  for (int t = 0; t < 8; ++t) {
    if (t < 7) stage(t + 1, cur ^ 1);
    int lo = l & 15, hi = l >> 4;
    bf16x8 af[2], bb[5];
#pragma unroll
    for (int m = 0; m < 2; ++m)
      af[m] = *(const bf16x8*)(lA[cur] + (w * 32 + m * 16 + lo) * 32 + hi * 8);
#pragma unroll
    for (int n = 0; n < 5; ++n)
      bb[n] = *(const bf16x8*)(lB[cur] + (n * 16 + lo) * 32 + hi * 8);
#pragma unroll
    for (int m = 0; m < 2; ++m)
#pragma unroll
      for (int n = 0; n < 5; ++n)
        acc[m][n] = __builtin_amdgcn_mfma_f32_16x16x32_bf16(af[m], bb[n], acc[m][n], 0, 0, 0);
    asm volatile("s_waitcnt vmcnt(0)" ::: "memory");
    __syncthreads();
    cur ^= 1;
  }
  int lo = l & 15, g = l >> 4;
#pragma unroll
  for (int m = 0; m < 2; ++m) {
    float di[4];
#pragma unroll
    for (int r = 0; r < 4; ++r) {
      float dv = __shfl(acc[m][4][r], (l & 48), 64);  // denom from lane lo==0 of group
      di[r] = 1.f / dv;
    }
#pragma unroll
    for (int n = 0; n < 4; ++n) {
      int col = (bh & 15) * 64 + n * 16 + lo;
#pragma unroll
      for (int r = 0; r < 4; ++r) {
        long tok = tokb + m0 + w * 32 + m * 16 + g * 4 + r;
        attn[tok * 1024 + col] = f2bf(acc[m][n][r] * di[r]);
      }
    }
  }
}

extern "C" void kernel_launch(void* const* d_in, const int* in_sizes, int n_in,
                              void* d_out, int out_size, void* d_ws, size_t ws_size,
                              hipStream_t stream) {
  const float* X = (const float*)d_in[0];
  const float* mask = (const float*)d_in[1];
  const float* Wq = (const float*)d_in[2];
  const float* bq = (const float*)d_in[3];
  const float* Wk = (const float*)d_in[4];
  const float* bk = (const float*)d_in[5];
  const float* Wv = (const float*)d_in[6];
  const float* bv = (const float*)d_in[7];
  const float* Wff = (const float*)d_in[8];
  const float* bff = (const float*)d_in[9];
  const float* proj = (const float*)d_in[10];
  float* out = (float*)d_out;

  char* p = (char*)d_ws;
  u16* Xbf = (u16*)p;   p += 16777216;   // [8192][1024] bf16
  u16* Wqkv = (u16*)p;  p += 6291456;    // [3072][1024]
  u16* Wffb = (u16*)p;  p += 2097152;    // [1024][1024]
  u16* Pbf = (u16*)p;   p += 32768;      // bf16(proj/8) [256][64]
  u16* Qbf = (u16*)p;   p += 16777216;
  u16* Kbf = (u16*)p;   p += 16777216;
  u16* Vt = (u16*)p;    p += 16777216;   // [bh*64+e][4096] (mask applied)
  u16* qp = (u16*)p;    p += 67108864;   // [bh][4096][256]
  u16* kpt = (u16*)p;   p += 67108864;   // [bh][256][4096]
  u16* ctxb = (u16*)p;  p += 1310720;    // [bh][80][256]: rows 0-63 ctx^T, 64 k_sum, 65-79 zero
  unsigned* menc = (unsigned*)p; p += 256;
  float* ctxp = (float*)Qbf;  // 16.78MB partials, reuse (Qbf dead after feat<0>)
  u16* attn = Xbf;            // reuse (Xbf dead after qkv)

  hipMemsetAsync(menc, 0, 128, stream);
  cvt_bf<<<8192, 256, 0, stream>>>(X, Xbf, 8388608L, 1.f);
  cvt_bf<<<1024, 256, 0, stream>>>(Wq, Wqkv, 1048576L, 1.f);
  cvt_bf<<<1024, 256, 0, stream>>>(Wk, Wqkv + 1048576, 1048576L, 1.f);
  cvt_bf<<<1024, 256, 0, stream>>>(Wv, Wqkv + 2097152, 1048576L, 1.f);
  cvt_bf<<<1024, 256, 0, stream>>>(Wff, Wffb, 1048576L, 1.f);
  cvt_bf<<<16, 256, 0, stream>>>(proj, Pbf, 16384L, 0.125f);
  gemm8p<0, 24><<<768, 512, 0, stream>>>(Xbf, Wqkv, bq, bk, bv, mask, Qbf, Kbf, Vt, nullptr, nullptr);
  feat_kernel<0><<<dim3(128, 16), 256, 0, stream>>>(Qbf, Pbf, mask, menc, qp);
  feat_kernel<1><<<dim3(128, 16), 256, 0, stream>>>(Kbf, Pbf, mask, menc, kpt);
  feat_kernel<2><<<dim3(128, 16), 256, 0, stream>>>(Kbf, Pbf, mask, menc, kpt);
  ksum_kernel<<<512, 256, 0, stream>>>(kpt, ctxb);
  ctx_gemm<<<dim3(32, 8), 256, 0, stream>>>(kpt, Vt, ctxp);
  ctx_reduce<<<2048, 256, 0, stream>>>(ctxp, ctxb);
  attn_gemm<<<dim3(32, 32), 256, 0, stream>>>(qp, ctxb, attn);
  gemm8p<1, 8><<<256, 512, 0, stream>>>(attn, Wffb, nullptr, nullptr, nullptr, nullptr,
                                        nullptr, nullptr, nullptr, out, bff);
}

// Round 3
// 208.986 us; speedup vs baseline: 1.3322x; 1.2018x over previous
//
#include <hip/hip_runtime.h>
#include <math.h>

typedef unsigned short u16;
typedef short bf16x8 __attribute__((ext_vector_type(8)));   // 8 bf16 in 4 VGPR
typedef float f32x4 __attribute__((ext_vector_type(4)));
typedef u16 u16x4 __attribute__((ext_vector_type(4)));

#define RATIO 0.0625f   // 256^-0.5
#define EPSK 1e-4f
#define LOG2E 1.44269504f

__device__ __forceinline__ float bf2f(u16 u) {
  return __uint_as_float(((unsigned)u) << 16);
}
__device__ __forceinline__ u16 f2bf(float f) {
  unsigned x = __float_as_uint(f);
  x = x + 0x7fffu + ((x >> 16) & 1u);   // RNE
  return (u16)(x >> 16);
}
__device__ __forceinline__ unsigned cvtpk(float a, float b) {  // [lo=bf16(a), hi=bf16(b)]
  unsigned d;
  asm("v_cvt_pk_bf16_f32 %0, %1, %2" : "=v"(d) : "v"(a), "v"(b));
  return d;
}
__device__ __forceinline__ unsigned fenc(float f) {  // order-preserving float->uint
  unsigned u = __float_as_uint(f);
  return (u & 0x80000000u) ? ~u : (u | 0x80000000u);
}
__device__ __forceinline__ float fdec(unsigned e) {
  return (e & 0x80000000u) ? __uint_as_float(e & 0x7fffffffu) : __uint_as_float(~e);
}

using as1v = __attribute__((address_space(1))) void;
using as3v = __attribute__((address_space(3))) void;
__device__ __forceinline__ void gl_lds16(const void* g, void* l) {
  __builtin_amdgcn_global_load_lds((as1v*)g, (as3v*)l, 16, 0, 0);
}

// ---------------- f32 -> bf16 convert (optionally scaled) ----------------
__global__ __launch_bounds__(256) void cvt_bf(const float* __restrict__ in, u16* __restrict__ out,
                                              long n, float scale) {
  long i = ((long)blockIdx.x * 256 + threadIdx.x) * 4;
  if (i >= n) return;
  f32x4 v = *(const f32x4*)(in + i);
  u16x4 o;
#pragma unroll
  for (int j = 0; j < 4; ++j) o[j] = f2bf(v[j] * scale);
  *(u16x4*)(out + i) = o;
}

// =====================================================================
// 8-phase GEMM, 256x128 tile, BK=64, 8 waves (4M x 2N), 64x64 per wave.
// Triple-buffered LDS; counted vmcnt(6); read-side XOR swizzle with
// pre-swizzled global source. EPI 0 = qkv, EPI 1 = ff.
// =====================================================================
template <int EPI, int NB>
__global__ __launch_bounds__(512, 1) void gemm8p(
    const u16* __restrict__ A, const u16* __restrict__ Bw,
    const float* __restrict__ bq, const float* __restrict__ bk,
    const float* __restrict__ bv, const float* __restrict__ mask,
    u16* __restrict__ Q, u16* __restrict__ Kb, u16* __restrict__ Vt,
    float* __restrict__ Of, const float* __restrict__ bff) {
  __shared__ __align__(16) u16 lds[3 * 3 * 8192];  // 144 KB
  const int nt = 16;  // K = 1024, BK = 64
  int tid = threadIdx.x;
  int l = tid & 63, w = tid >> 6;
  int wm = w >> 1, wn = w & 1;
  int lo = l & 15, hi = l >> 4;
  int bid = blockIdx.x;
  int swz = (bid & 7) * ((NB * 32) / 8) + (bid >> 3);  // bijective XCD swizzle
  long m0 = (long)(swz / NB) * 256;
  long c0 = (long)(swz % NB) * 128;
  int srow = tid >> 3;                              // staging row 0..63
  int sce = ((tid & 7) ^ ((tid >> 3) & 7)) * 8;     // pre-swizzled source col
  f32x4 acc[4][4] = {};

  auto stageA = [&](int t) {
    u16* ub = (u16*)lds + (t % 3) * 24576;
    long k0 = (long)t * 64;
#pragma unroll
    for (int u = 0; u < 2; ++u)
#pragma unroll
      for (int j = 0; j < 2; ++j) {
        long row = m0 + u * 128 + j * 64 + srow;
        gl_lds16(A + row * 1024 + k0 + sce, ub + u * 8192 + j * 4096 + tid * 8);
      }
  };
  auto stageB = [&](int t) {
    u16* ub = (u16*)lds + (t % 3) * 24576 + 16384;
    long k0 = (long)t * 64;
#pragma unroll
    for (int j = 0; j < 2; ++j) {
      long row = c0 + j * 64 + srow;
      gl_lds16(Bw + row * 1024 + k0 + sce, ub + j * 4096 + tid * 8);
    }
  };

  stageA(0); stageB(0);
  stageA(1); stageB(1);
  asm volatile("s_waitcnt vmcnt(6)" ::: "memory");
  __builtin_amdgcn_s_barrier();
  __builtin_amdgcn_sched_barrier(0);

  bf16x8 areg[4][2], breg[2][2];
  int arb = (wm & 1) * 64;
  for (int t = 0; t < nt; ++t) {
    const u16* Au = (const u16*)lds + (t % 3) * 24576 + (wm >> 1) * 8192;
    const u16* Bu = (const u16*)lds + (t % 3) * 24576 + 16384;
#pragma unroll
    for (int mf = 0; mf < 4; ++mf) {
      int lrow = arb + mf * 16 + lo;
#pragma unroll
      for (int kk = 0; kk < 2; ++kk)
        areg[mf][kk] = *(const bf16x8*)(Au + lrow * 64 + ((kk * 32 + hi * 8) ^ ((lo & 7) << 3)));
    }
#pragma unroll
    for (int nf = 0; nf < 2; ++nf) {
      int lrow = wn * 64 + nf * 16 + lo;
#pragma unroll
      for (int kk = 0; kk < 2; ++kk)
        breg[nf][kk] = *(const bf16x8*)(Bu + lrow * 64 + ((kk * 32 + hi * 8) ^ ((lo & 7) << 3)));
    }
    if (t + 2 < nt) stageA(t + 2);
    __builtin_amdgcn_s_barrier();
    asm volatile("s_waitcnt lgkmcnt(0)" ::: "memory");
    __builtin_amdgcn_sched_barrier(0);
    __builtin_amdgcn_s_setprio(1);
#pragma unroll
    for (int mf = 0; mf < 4; ++mf)
#pragma unroll
      for (int nf = 0; nf < 2; ++nf)
#pragma unroll
        for (int kk = 0; kk < 2; ++kk)
          acc[mf][nf] = __builtin_amdgcn_mfma_f32_16x16x32_bf16(areg[mf][kk], breg[nf][kk],
                                                                acc[mf][nf], 0, 0, 0);
    __builtin_amdgcn_s_setprio(0);
    __builtin_amdgcn_s_barrier();
    __builtin_amdgcn_sched_barrier(0);
#pragma unroll
    for (int nf = 0; nf < 2; ++nf) {
      int lrow = wn * 64 + (2 + nf) * 16 + lo;
#pragma unroll
      for (int kk = 0; kk < 2; ++kk)
        breg[nf][kk] = *(const bf16x8*)(Bu + lrow * 64 + ((kk * 32 + hi * 8) ^ ((lo & 7) << 3)));
    }
    if (t + 2 < nt) {
      stageB(t + 2);
      asm volatile("s_waitcnt vmcnt(6)" ::: "memory");
    } else if (t + 1 < nt) {
      asm volatile("s_waitcnt vmcnt(0)" ::: "memory");
    }
    __builtin_amdgcn_s_barrier();
    asm volatile("s_waitcnt lgkmcnt(0)" ::: "memory");
    __builtin_amdgcn_sched_barrier(0);
    __builtin_amdgcn_s_setprio(1);
#pragma unroll
    for (int mf = 0; mf < 4; ++mf)
#pragma unroll
      for (int nf = 0; nf < 2; ++nf)
#pragma unroll
        for (int kk = 0; kk < 2; ++kk)
          acc[mf][2 + nf] = __builtin_amdgcn_mfma_f32_16x16x32_bf16(areg[mf][kk], breg[nf][kk],
                                                                    acc[mf][2 + nf], 0, 0, 0);
    __builtin_amdgcn_s_setprio(0);
    __builtin_amdgcn_s_barrier();
    __builtin_amdgcn_sched_barrier(0);
  }

  long rowb = m0 + wm * 64;
  if (EPI == 0) {
    int wsel = (int)(c0 >> 10);  // 0=Q 1=K 2=V
    long cw = c0 & 1023;
    if (wsel < 2) {
      const float* bias = wsel ? bk : bq;
      u16* O = wsel ? Kb : Q;
#pragma unroll
      for (int mf = 0; mf < 4; ++mf)
#pragma unroll
        for (int nf = 0; nf < 4; ++nf) {
          long col = cw + wn * 64 + nf * 16 + lo;
          float bi = bias[col];
#pragma unroll
          for (int r = 0; r < 4; ++r) {
            long row = rowb + mf * 16 + hi * 4 + r;
            O[row * 1024 + col] = f2bf(acc[mf][nf][r] + bi);
          }
        }
    } else {
#pragma unroll
      for (int mf = 0; mf < 4; ++mf) {
        long t4 = rowb + mf * 16 + hi * 4;
        long b = t4 >> 12;
        long nn = t4 & 4095;
#pragma unroll
        for (int nf = 0; nf < 4; ++nf) {
          long col = cw + wn * 64 + nf * 16 + lo;
          float bi = bv[col];
          long h = col >> 6, e = col & 63;
          u16x4 pk;
#pragma unroll
          for (int r = 0; r < 4; ++r) pk[r] = f2bf((acc[mf][nf][r] + bi) * mask[t4 + r]);
          *(u16x4*)&Vt[((b * 16 + h) * 64 + e) * 4096 + nn] = pk;
        }
      }
    }
  } else {
#pragma unroll
    for (int mf = 0; mf < 4; ++mf)
#pragma unroll
      for (int nf = 0; nf < 4; ++nf) {
        long col = c0 + wn * 64 + nf * 16 + lo;
        float bi = bff[col];
#pragma unroll
        for (int r = 0; r < 4; ++r) {
          long row = rowb + mf * 16 + hi * 4 + r;
          Of[row * 1024 + col] = acc[mf][nf][r] + bi;
        }
      }
  }
}

// ---------------- key global max: mm = max over (n,r) of mask*dd ----------------
__global__ __launch_bounds__(256) void keymax_kernel(
    const u16* __restrict__ K, const u16* __restrict__ Pbf,
    const float* __restrict__ mask, unsigned* __restrict__ menc) {
  __shared__ u16 lP[256 * 64];  // 32KB
  __shared__ u16 lQ[64 * 64];   // 8KB
  __shared__ float smask[64];
  __shared__ float swmax[4];
  int tid = threadIdx.x, l = tid & 63, w = tid >> 6;
  int h = blockIdx.y;
  long t0 = (long)blockIdx.x * 64;
  int bh = (int)(t0 >> 12) * 16 + h;
#pragma unroll
  for (int i = 0; i < 8; ++i) {
    int ch = w * 8 + i;
    gl_lds16(Pbf + (long)(ch * 8 + (l >> 3)) * 64 + (l & 7) * 8, lP + ch * 512);
  }
#pragma unroll
  for (int i = 0; i < 2; ++i) {
    int ch = w * 2 + i;
    long tok = t0 + ch * 8 + (l >> 3);
    gl_lds16(K + tok * 1024 + (long)h * 64 + (l & 7) * 8, lQ + ch * 512);
  }
  if (tid < 64) smask[tid] = mask[t0 + tid];
  asm volatile("s_waitcnt vmcnt(0)" ::: "memory");
  __syncthreads();
  f32x4 acc[4][4] = {};
  int lo = l & 15, hi = l >> 4;
#pragma unroll
  for (int k2 = 0; k2 < 2; ++k2) {
    bf16x8 af[4], bb[4];
#pragma unroll
    for (int m = 0; m < 4; ++m)
      af[m] = *(const bf16x8*)(lQ + (m * 16 + lo) * 64 + k2 * 32 + hi * 8);
#pragma unroll
    for (int n = 0; n < 4; ++n)
      bb[n] = *(const bf16x8*)(lP + (w * 64 + n * 16 + lo) * 64 + k2 * 32 + hi * 8);
#pragma unroll
    for (int m = 0; m < 4; ++m)
#pragma unroll
      for (int n = 0; n < 4; ++n)
        acc[m][n] = __builtin_amdgcn_mfma_f32_16x16x32_bf16(af[m], bb[n], acc[m][n], 0, 0, 0);
  }
  float mm = -3.4e38f;
#pragma unroll
  for (int m = 0; m < 4; ++m)
#pragma unroll
    for (int r = 0; r < 4; ++r) {
      float mv = smask[m * 16 + hi * 4 + r];
#pragma unroll
      for (int n = 0; n < 4; ++n) mm = fmaxf(mm, mv * acc[m][n][r]);
    }
#pragma unroll
  for (int s = 1; s < 64; s <<= 1) mm = fmaxf(mm, __shfl_xor(mm, s, 64));
  if (l == 0) swmax[w] = mm;
  __syncthreads();
  if (tid == 0) {
    float bm = fmaxf(fmaxf(swmax[0], swmax[1]), fmaxf(swmax[2], swmax[3]));
    atomicMax(&menc[bh], fenc(bm));
  }
}

// =====================================================================
// kctx: per (bh, 256-token chunk): recompute kp in LDS, accumulate
// ctx[r][e] partials + ksum partials. Replaces feat<2>+ksum+ctx_gemm.
// =====================================================================
__global__ __launch_bounds__(256) void kctx(
    const u16* __restrict__ Kg, const u16* __restrict__ Pbf,
    const u16* __restrict__ Vt, const float* __restrict__ mask,
    const unsigned* __restrict__ menc,
    float* __restrict__ part, float* __restrict__ part_ks) {
  __shared__ __align__(16) u16 projL[256 * 64];  // 32KB
  __shared__ __align__(16) u16 KL[256 * 64];     // 32KB
  __shared__ __align__(16) u16 VL[64 * 256];     // 32KB
  __shared__ __align__(16) u16 kpL[256 * 64];    // 32KB  [r][tok]
  __shared__ float sdiag[256];
  __shared__ float smask[256];
  int tid = threadIdx.x, l = tid & 63, wq = tid >> 6;
  int lo = l & 15, hi = l >> 4;
  int bh = blockIdx.x, ck = blockIdx.y;
  int b = bh >> 4, h = bh & 15;
  long tg0 = (long)b * 4096 + (long)ck * 256;
  int rq = wq * 64;
  // stage proj + K (64-elem rows, swizzled source)
#pragma unroll
  for (int i = 0; i < 8; ++i) {
    int c = wq * 8 + i;
    int row = c * 8 + (l >> 3);
    int sc_ = ((l & 7) * 8) ^ ((row & 7) << 3);
    gl_lds16(Pbf + (long)row * 64 + sc_, projL + c * 512);
    gl_lds16(Kg + (tg0 + row) * 1024 + (long)h * 64 + sc_, KL + c * 512);
  }
  // stage Vt tile [64 e][256 n] (512B rows, swizzled)
#pragma unroll
  for (int i = 0; i < 8; ++i) {
    int c = wq * 8 + i;
    int e = 2 * c + (l >> 5);
    int sc_ = ((l & 31) * 8) ^ ((e & 7) << 3);
    gl_lds16(Vt + ((long)bh * 64 + e) * 4096 + (long)ck * 256 + sc_, VL + c * 512);
  }
  asm volatile("s_waitcnt vmcnt(0)" ::: "memory");
  __syncthreads();
  // per-token diag + mask
  {
    float s = 0.f;
#pragma unroll
    for (int j = 0; j < 8; ++j) {
      bf16x8 v = *(const bf16x8*)(KL + tid * 64 + ((j * 8) ^ ((tid & 7) << 3)));
#pragma unroll
      for (int e = 0; e < 8; ++e) {
        float f = bf2f((u16)v[e]);
        s += f * f;
      }
    }
    sdiag[tid] = s * (1.f / 128.f);
    smask[tid] = mask[tg0 + tid];
  }
  __syncthreads();
  float M = fdec(menc[bh]);
  bf16x8 ones;
#pragma unroll
  for (int e = 0; e < 8; ++e) ones[e] = (short)0x3F80;
  f32x4 acc2[4][4] = {};
  f32x4 acc_ks[4] = {};
  for (int sc = 0; sc < 4; ++sc) {
    // dd (normal): D[tok][r], A = K rows tok, B = proj rows r
    f32x4 acc[4][4] = {};
#pragma unroll
    for (int kk = 0; kk < 2; ++kk) {
      bf16x8 aK[4], bP[4];
#pragma unroll
      for (int m = 0; m < 4; ++m)
        aK[m] = *(const bf16x8*)(KL + (sc * 64 + m * 16 + lo) * 64 +
                                 ((kk * 32 + hi * 8) ^ ((lo & 7) << 3)));
#pragma unroll
      for (int nf = 0; nf < 4; ++nf)
        bP[nf] = *(const bf16x8*)(projL + (rq + nf * 16 + lo) * 64 +
                                  ((kk * 32 + hi * 8) ^ ((lo & 7) << 3)));
#pragma unroll
      for (int m = 0; m < 4; ++m)
#pragma unroll
        for (int nf = 0; nf < 4; ++nf)
          acc[m][nf] = __builtin_amdgcn_mfma_f32_16x16x32_bf16(aK[m], bP[nf], acc[m][nf], 0, 0, 0);
    }
    // epilogue: kp = RATIO*(exp(mv*dd - mv^2*diag - M)+eps) -> kpL[r][tok]
#pragma unroll
    for (int m = 0; m < 4; ++m) {
      int tb = m * 16 + hi * 4;
      float mv[4], dg[4];
#pragma unroll
      for (int r = 0; r < 4; ++r) {
        int tk = sc * 64 + tb + r;
        mv[r] = smask[tk];
        dg[r] = sdiag[tk];
      }
#pragma unroll
      for (int nf = 0; nf < 4; ++nf) {
        int rr = rq + nf * 16 + lo;
        float v[4];
#pragma unroll
        for (int r = 0; r < 4; ++r) {
          float x = mv[r] * acc[m][nf][r] - mv[r] * mv[r] * dg[r] - M;
          v[r] = RATIO * (__builtin_exp2f(x * LOG2E) + EPSK);
        }
        uint2 pk;
        pk.x = cvtpk(v[0], v[1]);
        pk.y = cvtpk(v[2], v[3]);
        *(uint2*)(kpL + rr * 64 + (tb ^ ((lo & 7) << 3))) = pk;
      }
    }
    // ctx MFMA: D[r][e] += kp[r][n] * Vt[e][n]; + ksum via ones
#pragma unroll
    for (int kk = 0; kk < 2; ++kk) {
      bf16x8 aC[4], bV[4];
#pragma unroll
      for (int m = 0; m < 4; ++m)
        aC[m] = *(const bf16x8*)(kpL + (rq + m * 16 + lo) * 64 +
                                 ((kk * 32 + hi * 8) ^ ((lo & 7) << 3)));
#pragma unroll
      for (int nf = 0; nf < 4; ++nf)
        bV[nf] = *(const bf16x8*)(VL + (nf * 16 + lo) * 256 +
                                  ((sc * 64 + kk * 32 + hi * 8) ^ ((lo & 7) << 3)));
#pragma unroll
      for (int m = 0; m < 4; ++m) {
        acc_ks[m] = __builtin_amdgcn_mfma_f32_16x16x32_bf16(aC[m], ones, acc_ks[m], 0, 0, 0);
#pragma unroll
        for (int nf = 0; nf < 4; ++nf)
          acc2[m][nf] = __builtin_amdgcn_mfma_f32_16x16x32_bf16(aC[m], bV[nf], acc2[m][nf], 0, 0, 0);
      }
    }
  }
  // write partials: part[(bh*16+ck)*64 + e][r] f32, r contiguous
  long pb = ((long)bh * 16 + ck) * 64;
#pragma unroll
  for (int m = 0; m < 4; ++m) {
    int r0 = rq + m * 16 + hi * 4;
#pragma unroll
    for (int nf = 0; nf < 4; ++nf) {
      int e = nf * 16 + lo;
      *(f32x4*)&part[(pb + e) * 256 + r0] = acc2[m][nf];
    }
    if (lo == 0)
      *(f32x4*)&part_ks[((long)bh * 16 + ck) * 256 + r0] = acc_ks[m];
  }
}

// ---------------- reduce partials -> ctxb [bh][80][256] bf16 ----------------
__global__ __launch_bounds__(256) void ctx_reduce2(const float* __restrict__ part,
                                                   const float* __restrict__ part_ks,
                                                   u16* __restrict__ ctxb) {
  int bid = blockIdx.x;
  int bh = bid / 80, j = bid % 80;
  int r = threadIdx.x;
  float s = 0.f;
  if (j < 64) {
#pragma unroll
    for (int c = 0; c < 16; ++c) s += part[(((long)bh * 16 + c) * 64 + j) * 256 + r];
  } else if (j == 64) {
#pragma unroll
    for (int c = 0; c < 16; ++c) s += part_ks[((long)bh * 16 + c) * 256 + r];
  }
  ctxb[((long)bh * 80 + j) * 256 + r] = f2bf(s);
}

// =====================================================================
// qattn: per (bh, 128-token block): recompute qp in LDS (dd transposed,
// cross-wave rowmax), then D2[j][tok] = ctxb[j][r]*qp[tok][r]; j=64 row
// is the denominator (in-lane). Replaces feat<0>+attn_gemm.
// =====================================================================
__global__ __launch_bounds__(256) void qattn(
    const u16* __restrict__ Qg, const u16* __restrict__ Pbf,
    const u16* __restrict__ ctxbg, u16* __restrict__ attn) {
  __shared__ __align__(16) u16 L[69632];  // proj 16384 | ctxb 20480 | Q/qp 32768
  __shared__ float sdiagq[128];
  __shared__ float sredq[4 * 128];
  u16* projL = L;
  u16* CL = L + 16384;
  u16* QL = L + 36864;   // overlaid by qp after the rowmax barrier
  u16* qpL = L + 36864;  // [128 tok][256 r]
  int tid = threadIdx.x, l = tid & 63, wq = tid >> 6;
  int lo = l & 15, hi = l >> 4;
  int bh = blockIdx.x;
  int b = bh >> 4, h = bh & 15;
  long tokb = (long)b * 4096 + (long)blockIdx.y * 128;
  int rq = wq * 64, tq = wq * 32;
  // stage proj (swizzled)
#pragma unroll
  for (int i = 0; i < 8; ++i) {
    int c = wq * 8 + i;
    int row = c * 8 + (l >> 3);
    int sc_ = ((l & 7) * 8) ^ ((row & 7) << 3);
    gl_lds16(Pbf + (long)row * 64 + sc_, projL + c * 512);
  }
  // stage Q tile [128][64] (swizzled)
#pragma unroll
  for (int i = 0; i < 4; ++i) {
    int c = wq * 4 + i;
    int row = c * 8 + (l >> 3);
    int sc_ = ((l & 7) * 8) ^ ((row & 7) << 3);
    gl_lds16(Qg + (tokb + row) * 1024 + (long)h * 64 + sc_, QL + c * 512);
  }
  // stage ctxb tile [80][256] (swizzled)
#pragma unroll
  for (int i = 0; i < 10; ++i) {
    int c = wq * 10 + i;
    int j = 2 * c + (l >> 5);
    int sc_ = ((l & 31) * 8) ^ ((j & 7) << 3);
    gl_lds16(ctxbg + ((long)bh * 80 + j) * 256 + sc_, CL + c * 512);
  }
  asm volatile("s_waitcnt vmcnt(0)" ::: "memory");
  __syncthreads();
  // diag per token (threads 0-127)
  if (tid < 128) {
    float s = 0.f;
#pragma unroll
    for (int j = 0; j < 8; ++j) {
      bf16x8 v = *(const bf16x8*)(QL + tid * 64 + ((j * 8) ^ ((tid & 7) << 3)));
#pragma unroll
      for (int e = 0; e < 8; ++e) {
        float f = bf2f((u16)v[e]);
        s += f * f;
      }
    }
    sdiagq[tid] = s * (1.f / 128.f);
  }
  // dd transposed: D[r][tok], A = proj rows r (wave quadrant), B = Q rows tok
  f32x4 acc[4][8];
#pragma unroll
  for (int m = 0; m < 4; ++m)
#pragma unroll
    for (int nf = 0; nf < 8; ++nf) acc[m][nf] = f32x4{0.f, 0.f, 0.f, 0.f};
#pragma unroll
  for (int kk = 0; kk < 2; ++kk) {
    bf16x8 aP[4], bQ[8];
#pragma unroll
    for (int m = 0; m < 4; ++m)
      aP[m] = *(const bf16x8*)(projL + (rq + m * 16 + lo) * 64 +
                               ((kk * 32 + hi * 8) ^ ((lo & 7) << 3)));
#pragma unroll
    for (int nf = 0; nf < 8; ++nf)
      bQ[nf] = *(const bf16x8*)(QL + (nf * 16 + lo) * 64 +
                                ((kk * 32 + hi * 8) ^ ((lo & 7) << 3)));
#pragma unroll
    for (int m = 0; m < 4; ++m)
#pragma unroll
      for (int nf = 0; nf < 8; ++nf)
        acc[m][nf] = __builtin_amdgcn_mfma_f32_16x16x32_bf16(aP[m], bQ[nf], acc[m][nf], 0, 0, 0);
  }
  // wave-local rowmax per token (max over this wave's 64 r)
#pragma unroll
  for (int nf = 0; nf < 8; ++nf) {
    float vm = acc[0][nf][0];
#pragma unroll
    for (int m = 0; m < 4; ++m)
#pragma unroll
      for (int r = 0; r < 4; ++r) vm = fmaxf(vm, acc[m][nf][r]);
    vm = fmaxf(vm, __shfl_xor(vm, 16, 64));
    vm = fmaxf(vm, __shfl_xor(vm, 32, 64));
    if (hi == 0) sredq[wq * 128 + nf * 16 + lo] = vm;
  }
  __syncthreads();  // also separates QL reads from qp writes
  // final rowmax + epilogue -> qpL[tok][r]
#pragma unroll
  for (int nf = 0; nf < 8; ++nf) {
    int tk = nf * 16 + lo;
    float rm = fmaxf(fmaxf(sredq[tk], sredq[128 + tk]),
                     fmaxf(sredq[256 + tk], sredq[384 + tk]));
    float dg = sdiagq[tk];
#pragma unroll
    for (int m = 0; m < 4; ++m) {
      int r0 = rq + m * 16 + hi * 4;
      float v[4];
#pragma unroll
      for (int r = 0; r < 4; ++r) {
        float x = acc[m][nf][r] - dg - rm;
        v[r] = RATIO * (__builtin_exp2f(x * LOG2E) + EPSK);
      }
      uint2 pk;
      pk.x = cvtpk(v[0], v[1]);
      pk.y = cvtpk(v[2], v[3]);
      *(uint2*)(qpL + tk * 256 + (r0 ^ ((lo & 7) << 3))) = pk;
    }
  }
  __syncthreads();
  // D2[j][tok] = sum_r ctxb[j][r] * qp[tok][r]; wave owns 32 tok
  f32x4 acc2[5][2];
#pragma unroll
  for (int m = 0; m < 5; ++m)
#pragma unroll
    for (int n = 0; n < 2; ++n) acc2[m][n] = f32x4{0.f, 0.f, 0.f, 0.f};
#pragma unroll
  for (int ks = 0; ks < 8; ++ks) {
    bf16x8 aC[5], bQp[2];
#pragma unroll
    for (int m = 0; m < 5; ++m)
      aC[m] = *(const bf16x8*)(CL + (m * 16 + lo) * 256 +
                               ((ks * 32 + hi * 8) ^ ((lo & 7) << 3)));
#pragma unroll
    for (int n = 0; n < 2; ++n)
      bQp[n] = *(const bf16x8*)(qpL + (tq + n * 16 + lo) * 256 +
                                ((ks * 32 + hi * 8) ^ ((lo & 7) << 3)));
#pragma unroll
    for (int m = 0; m < 5; ++m)
#pragma unroll
      for (int n = 0; n < 2; ++n)
        acc2[m][n] = __builtin_amdgcn_mfma_f32_16x16x32_bf16(aC[m], bQp[n], acc2[m][n], 0, 0, 0);
  }
  // epilogue: denom at j=64 (m=4, hi=0, reg=0) -> broadcast via shfl(lane = lo)
#pragma unroll
  for (int n = 0; n < 2; ++n) {
    float dv = __shfl(acc2[4][n][0], lo, 64);
    float di = 1.f / dv;
    long tok = tokb + tq + n * 16 + lo;
#pragma unroll
    for (int m = 0; m < 4; ++m) {
      int j0 = m * 16 + hi * 4;
      uint2 pk;
      pk.x = cvtpk(acc2[m][n][0] * di, acc2[m][n][1] * di);
      pk.y = cvtpk(acc2[m][n][2] * di, acc2[m][n][3] * di);
      *(uint2*)&attn[tok * 1024 + (long)h * 64 + j0] = pk;
    }
  }
}

extern "C" void kernel_launch(void* const* d_in, const int* in_sizes, int n_in,
                              void* d_out, int out_size, void* d_ws, size_t ws_size,
                              hipStream_t stream) {
  const float* X = (const float*)d_in[0];
  const float* mask = (const float*)d_in[1];
  const float* Wq = (const float*)d_in[2];
  const float* bq = (const float*)d_in[3];
  const float* Wk = (const float*)d_in[4];
  const float* bk = (const float*)d_in[5];
  const float* Wv = (const float*)d_in[6];
  const float* bv = (const float*)d_in[7];
  const float* Wff = (const float*)d_in[8];
  const float* bff = (const float*)d_in[9];
  const float* proj = (const float*)d_in[10];
  float* out = (float*)d_out;

  char* p = (char*)d_ws;
  u16* Xbf = (u16*)p;   p += 16777216;   // [8192][1024] bf16; reused as attn
  u16* Wqkv = (u16*)p;  p += 6291456;    // [3072][1024]
  u16* Wffb = (u16*)p;  p += 2097152;    // [1024][1024]
  u16* Pbf = (u16*)p;   p += 32768;      // bf16(proj/8) [256][64]
  u16* Qbf = (u16*)p;   p += 16777216;
  u16* Kbf = (u16*)p;   p += 16777216;
  u16* Vt = (u16*)p;    p += 16777216;   // [bh*64+e][4096] (mask applied)
  u16* ctxb = (u16*)p;  p += 1310720;    // [bh][80][256]
  unsigned* menc = (unsigned*)p; p += 256;
  float* part = (float*)p;    p += 33554432;  // [bh*16][64][256] f32
  float* part_ks = (float*)p; p += 524288;    // [bh*16][256] f32
  u16* attn = Xbf;

  hipMemsetAsync(menc, 0, 128, stream);
  cvt_bf<<<8192, 256, 0, stream>>>(X, Xbf, 8388608L, 1.f);
  cvt_bf<<<1024, 256, 0, stream>>>(Wq, Wqkv, 1048576L, 1.f);
  cvt_bf<<<1024, 256, 0, stream>>>(Wk, Wqkv + 1048576, 1048576L, 1.f);
  cvt_bf<<<1024, 256, 0, stream>>>(Wv, Wqkv + 2097152, 1048576L, 1.f);
  cvt_bf<<<1024, 256, 0, stream>>>(Wff, Wffb, 1048576L, 1.f);
  cvt_bf<<<16, 256, 0, stream>>>(proj, Pbf, 16384L, 0.125f);
  gemm8p<0, 24><<<768, 512, 0, stream>>>(Xbf, Wqkv, bq, bk, bv, mask, Qbf, Kbf, Vt, nullptr, nullptr);
  keymax_kernel<<<dim3(128, 16), 256, 0, stream>>>(Kbf, Pbf, mask, menc);
  kctx<<<dim3(32, 16), 256, 0, stream>>>(Kbf, Pbf, Vt, mask, menc, part, part_ks);
  ctx_reduce2<<<2560, 256, 0, stream>>>(part, part_ks, ctxb);
  qattn<<<dim3(32, 32), 256, 0, stream>>>(Qbf, Pbf, ctxb, attn);
  gemm8p<1, 8><<<256, 512, 0, stream>>>(attn, Wffb, nullptr, nullptr, nullptr, nullptr,
                                        nullptr, nullptr, nullptr, out, bff);
}